// Round 4
// baseline (75.536 us; speedup 1.0000x reference)
//
#include <hip/hip_runtime.h>
#include <math.h>

#define Bb   2
#define Vv   20000
#define Cc   9
#define KS   9
#define OUTn 16
#define NB   16

// Single fused kernel: 4 lanes per (b,v). Each lane prefetches its 4 neighbor
// rows (36 independent scalar loads), computes un-normalized softmax (safe:
// |xv-xn| << 88), accumulates partial s[9][9], quad DPP-shuffle reduce, each
// lane emits 4 of the 16 outputs via broadcast b128 LDS reads of W.
// adj==0: clamp row, zero via mask -> contributes exactly 0 to s (matches ref).
__global__ __launch_bounds__(256) void nlayer_kernel(
    const float* __restrict__ x,      // (B,V,C)
    const float* __restrict__ W,      // (C,KS,OUT)
    const int*   __restrict__ adj,    // (V,NB)
    float* __restrict__ out)          // (B,V,OUT)
{
    __shared__ float sW[Cc * KS * OUTn];   // 5184 B
    for (int i = threadIdx.x; i < Cc * KS * OUTn; i += 256) sW[i] = W[i];
    __syncthreads();

    int t    = blockIdx.x * 256 + threadIdx.x;   // grid exactly covers B*V*4
    int pair = t >> 2;                 // which (b,v)
    int sub  = t & 3;                  // lane within quad
    int b = pair / Vv;
    int v = pair - b * Vv;

    const float* xb = x + (size_t)b * Vv * Cc;

    // center row (same address across quad -> broadcast)
    float xv[Cc];
    #pragma unroll
    for (int c = 0; c < Cc; ++c) xv[c] = xb[(size_t)v * Cc + c];

    // this lane's 4 neighbors (16B-aligned int4)
    int4 av = *(const int4*)(adj + (size_t)v * NB + (sub << 2));
    int a[4] = {av.x, av.y, av.z, av.w};

    int deg = 0;
    #pragma unroll
    for (int i = 0; i < 4; ++i) deg += (a[i] != 0);

    // prefetch all 4 neighbor rows (36 independent loads, masked branchlessly)
    float xn[4][Cc];
    #pragma unroll
    for (int i = 0; i < 4; ++i) {
        int j = a[i];
        int row   = (j > 0) ? (j - 1) : 0;
        float msk = (j > 0) ? 1.0f : 0.0f;
        const float* xp = xb + (size_t)row * Cc;
        #pragma unroll
        for (int c = 0; c < Cc; ++c) xn[i][c] = xp[c] * msk;
    }

    float s[KS][Cc];
    #pragma unroll
    for (int k = 0; k < KS; ++k)
        #pragma unroll
        for (int c = 0; c < Cc; ++c) s[k][c] = 0.0f;

    #pragma unroll
    for (int i = 0; i < 4; ++i) {
        // un-normalized softmax: exp(xv-xn) directly (|d| < ~12, no overflow)
        float e[Cc];
        float sum = 0.0f;
        #pragma unroll
        for (int c = 0; c < Cc; ++c) { e[c] = __expf(xv[c] - xn[i][c]); sum += e[c]; }
        float inv = 1.0f / sum;

        #pragma unroll
        for (int k = 0; k < KS; ++k) {
            float qk = e[k] * inv;
            #pragma unroll
            for (int c = 0; c < Cc; ++c) s[k][c] = fmaf(qk, xn[i][c], s[k][c]);
        }
    }

    // quad reduction (xor 1, xor 2) — DPP cross-lane adds
    #pragma unroll
    for (int k = 0; k < KS; ++k) {
        #pragma unroll
        for (int c = 0; c < Cc; ++c) {
            float vv = s[k][c];
            vv += __shfl_xor(vv, 1);
            vv += __shfl_xor(vv, 2);
            s[k][c] = vv;
        }
    }
    deg += __shfl_xor(deg, 1);
    deg += __shfl_xor(deg, 2);
    float invdeg = (deg > 0) ? (1.0f / (float)deg) : 0.0f;

    // epilogue: this lane computes outputs [sub*4, sub*4+4)
    float acc0 = 0.f, acc1 = 0.f, acc2 = 0.f, acc3 = 0.f;
    #pragma unroll
    for (int c = 0; c < Cc; ++c) {
        #pragma unroll
        for (int k = 0; k < KS; ++k) {
            float sv = s[k][c];
            float4 w = *(const float4*)&sW[(c * KS + k) * OUTn + (sub << 2)];
            acc0 = fmaf(sv, w.x, acc0);
            acc1 = fmaf(sv, w.y, acc1);
            acc2 = fmaf(sv, w.z, acc2);
            acc3 = fmaf(sv, w.w, acc3);
        }
    }

    float4 r;
    r.x = fmaxf(acc0 * invdeg, 0.0f);
    r.y = fmaxf(acc1 * invdeg, 0.0f);
    r.z = fmaxf(acc2 * invdeg, 0.0f);
    r.w = fmaxf(acc3 * invdeg, 0.0f);
    *(float4*)(out + (size_t)pair * OUTn + (sub << 2)) = r;
}

extern "C" void kernel_launch(void* const* d_in, const int* in_sizes, int n_in,
                              void* d_out, int out_size, void* d_ws, size_t ws_size,
                              hipStream_t stream) {
    const float* x   = (const float*)d_in[0];
    const float* W   = (const float*)d_in[1];
    const int*   adj = (const int*)d_in[2];
    float*       out = (float*)d_out;

    const int total = Bb * Vv * 4;           // 160000 = 625 * 256 exactly
    const int block = 256;
    const int grid  = total / block;
    nlayer_kernel<<<grid, block, 0, stream>>>(x, W, adj, out);
}